// Round 7
// baseline (4001.341 us; speedup 1.0000x reference)
//
#include <hip/hip_runtime.h>
#include <math.h>

// Elman RNN: out[b][t][j] = H_t, H_t = tanh(X_t @ W_xh + H_{t-1} @ W_hh + b)
// Phase 1: proj_gemm writes Xp = X@W_xh + b into d_out's [B,S,H] region.
// Phase 2: ONE persistent kernel runs all 1024 steps.
//
// R11 = R10 (3130 us persist) + ONE change: MAC re-partition, 2 j-columns x
// 16-k per thread (was 1 j x 32 k).
//  - Theory: MAC is LDS-return-BW bound, not FMA bound. R10: 512 B of H per
//    thread -> 512 KB/CU/step over a 256 B/cy return path = 2048 cy (2x the
//    1024 cy FMA floor). Halving per-thread H reads (4b x 16k = 256 B)
//    halves MAC wall time. W regs stay 32 (2j x 16k), FMAs stay 128.
//  - Partition: jp = tid&15 (j = 2jp+jj), sw = (tid>>4)&3, wv = tid>>6,
//    kbase = wv*64 + sw*16. In-wave ds_read: 4 distinct addrs at 64B offsets
//    -> banks {0-3}/{16-19} x2 = 2-way aliasing (free, m136).
//  - Reduction: shfl_xor 16 then 32 combines the 4 in-wave k-segments;
//    lanes 0-15 write red[wv][b][2jp+jj]; epilogue unchanged (sum 16).
// PROTOCOL IS FROZEN at R4/R7: tid0 poll + s_sleep(2) + syncthreads release,
// 32-producer fetch_add flag, 4 barriers/step. R5/R6/R9 rewrites all LOST
// (R9: agent-atomic publishes write through to fabric -> +2x HBM traffic).
// Keepers: 1024 threads (R10: +12%), Xp prefetch at loop top, fast tanh,
// W strip asm-pinned (round-3 bug: compiler re-loaded W every step).
// NO __threadfence (round-3: full-L2 walks).
// Pre-committed failure read: persist >= 3050 us => MAC wasn't LDS-BW bound;
// residual is the frozen handshake chain -> overlap staging/MAC or declare
// the protocol floor.

#define B_SZ 32
#define S_SZ 1024
#define H_SZ 1024
#define K_SZ 1024

// ---------------- Phase 1: input projection GEMM (fp32) ----------------
#define BM 128
#define BN 128
#define BK 8

__global__ __launch_bounds__(256) void proj_gemm(
    const float* __restrict__ A,     // X   [M,K]
    const float* __restrict__ Bm,    // W_xh[K,N]
    const float* __restrict__ bias,  // [N]
    float* __restrict__ C,           // [M,N] (d_out Xp region)
    int M, int N, int K)
{
    __shared__ float As[BK][BM];   // transposed: As[k][m]
    __shared__ float Bs[BK][BN];

    const int tid  = threadIdx.x;
    const int row0 = blockIdx.y * BM;
    const int col0 = blockIdx.x * BN;
    const int tx = tid & 15;
    const int ty = tid >> 4;
    const int mBase = ty * 8;
    const int nBase = tx * 8;

    float acc[8][8];
    #pragma unroll
    for (int i = 0; i < 8; ++i)
        #pragma unroll
        for (int j = 0; j < 8; ++j) acc[i][j] = 0.f;

    for (int k0 = 0; k0 < K; k0 += BK) {
        {
            const int r  = tid >> 1;
            const int kq = (tid & 1) * 4;
            const float4 av = *(const float4*)(&A[(size_t)(row0 + r) * K + k0 + kq]);
            As[kq + 0][r] = av.x;
            As[kq + 1][r] = av.y;
            As[kq + 2][r] = av.z;
            As[kq + 3][r] = av.w;
            const int kr = tid >> 5;
            const int cq = (tid & 31) * 4;
            *(float4*)(&Bs[kr][cq]) =
                *(const float4*)(&Bm[(size_t)(k0 + kr) * N + col0 + cq]);
        }
        __syncthreads();

        #pragma unroll
        for (int kk = 0; kk < BK; ++kk) {
            float a[8], b[8];
            *(float4*)&a[0] = *(const float4*)&As[kk][mBase];
            *(float4*)&a[4] = *(const float4*)&As[kk][mBase + 4];
            *(float4*)&b[0] = *(const float4*)&Bs[kk][nBase];
            *(float4*)&b[4] = *(const float4*)&Bs[kk][nBase + 4];
            #pragma unroll
            for (int i = 0; i < 8; ++i)
                #pragma unroll
                for (int j = 0; j < 8; ++j)
                    acc[i][j] += a[i] * b[j];
        }
        __syncthreads();
    }

    #pragma unroll
    for (int i = 0; i < 8; ++i) {
        const int r = row0 + mBase + i;
        #pragma unroll
        for (int jq = 0; jq < 8; jq += 4) {
            const int c = col0 + nBase + jq;
            const float4 bv = *(const float4*)(&bias[c]);
            float4 o;
            o.x = acc[i][jq + 0] + bv.x;
            o.y = acc[i][jq + 1] + bv.y;
            o.z = acc[i][jq + 2] + bv.z;
            o.w = acc[i][jq + 3] + bv.w;
            *(float4*)(&C[(size_t)r * N + c]) = o;
        }
    }
}

// ---------------- init: zero the sync counters in d_ws ----------------
__global__ void init_cnt(unsigned int* __restrict__ cnt, int n) {
    int i = blockIdx.x * 256 + threadIdx.x;
    if (i < n) cnt[i] = 0u;
}

// fast tanh: tanh(x) = (e^{2x}-1)/(e^{2x}+1). Clamp keeps exp finite; output
// error ~1e-6 absolute — negligible vs the 3.9e-3 absmax budget.
__device__ __forceinline__ float fast_tanh(float x) {
    const float cx = fminf(fmaxf(x, -15.f), 15.f);
    const float e  = __expf(2.f * cx);
    return __fdividef(e - 1.f, e + 1.f);
}

// ---------------- Phase 2: persistent recurrence kernel ----------------
// 256 blocks x 1024 threads, 1 block/CU (4 waves/SIMD).
// Block (g = blockIdx&7, c = blockIdx>>3): batches [4g,4g+4), cols [32c,+32).
// MAC partition: jp = tid&15 (j = 2jp+jj, jj in {0,1}), sw = (tid>>4)&3,
// wv = tid>>6, kbase = wv*64 + sw*16 -> 4b x 16k x 2j per thread.
// W strip: w[jj][i] = W_hh[kbase+i][col0+2jp+jj], asm-pinned (32 regs).
// Per-step sync: cnt[g][t] arrival counters (32 producers per (g,t)).
// ALL cross-block H traffic uses agent-scope relaxed atomics (L3-coherent).
__global__ __launch_bounds__(1024, 4) void rnn_persist(
    float* __restrict__ HS,        // d_out [B][S][H]; Xp in, H out (in place)
    const float* __restrict__ W,   // W_hh [K][H]
    float* __restrict__ Hlast,     // d_out + B*S*H
    unsigned int* __restrict__ cnt // [8][S_SZ]
    )
{
    const int g    = blockIdx.x & 7;
    const int c    = blockIdx.x >> 3;
    const int col0 = c * 32;
    const int b0   = g * 4;
    const int tid  = threadIdx.x;
    const int jp   = tid & 15;          // j-pair: columns 2jp, 2jp+1
    const int sw   = (tid >> 4) & 3;    // in-wave k segment
    const int wv   = tid >> 6;          // wave 0..15
    const int kbase = wv * 64 + sw * 16;

    __shared__ __align__(16) float Hs[4][1024];     // H_{t-1} for 4 batches
    __shared__ float red[16][4][32];                // per-wave partials

    // Load W strip into registers (once), then pin: the asm makes the values
    // opaque so the compiler cannot sink/rematerialize the loads into the
    // t-loop (round-3 bug: W re-loaded every step otherwise).
    float w0[16], w1[16];
    {
        const float* wp = W + (size_t)kbase * H_SZ + col0 + 2 * jp;
        #pragma unroll
        for (int i = 0; i < 16; ++i) {
            w0[i] = wp[(size_t)i * H_SZ + 0];
            w1[i] = wp[(size_t)i * H_SZ + 1];
        }
        #pragma unroll
        for (int i = 0; i < 16; ++i) {
            asm volatile("" : "+v"(w0[i]));
            asm volatile("" : "+v"(w1[i]));
        }
    }

    unsigned int* flag = cnt + g * S_SZ;

    // epilogue map (tid < 128): b = tid>>5, jj = tid&31
    const int eb = tid >> 5;
    const int ej = tid & 31;

    for (int t = 0; t < S_SZ; ++t) {
        // ---- Xp prefetch: issue the epilogue's HBM read at loop top so its
        //      ~900cy miss hides under poll/stage/MAC. Plain load: this block
        //      is the only reader, and it reads strictly before overwrite.
        float xp = 0.f;
        size_t eidx = 0;
        if (tid < 128) {
            eidx = ((size_t)(b0 + eb) * S_SZ + t) * H_SZ + col0 + ej;
            xp = HS[eidx];
        }

        if (t > 0) {
            // ---- wait for H_{t-1} of this batch group (relaxed poll) ----
            if (tid == 0) {
                while (__hip_atomic_load(flag + (t - 1), __ATOMIC_RELAXED,
                                         __HIP_MEMORY_SCOPE_AGENT) < 32u) {
                    __builtin_amdgcn_s_sleep(2);
                }
            }
            __syncthreads();

            // ---- stage H_{t-1}[b0..b0+3][:] into LDS (16 KB) via 8-byte
            //      agent atomic loads (bypass L1/L2, read L3-fresh).
            //      2 qwords/thread; 8B lane stride (conflict-free). ----
            #pragma unroll
            for (int ch = 0; ch < 2; ++ch) {
                const int f8 = tid + ch * 1024;       // [0,2048) qword slots
                const int b  = f8 >> 9;               // 512 qwords per batch
                const int qw = f8 & 511;
                const unsigned long long* src = (const unsigned long long*)
                    (&HS[((size_t)(b0 + b) * S_SZ + (t - 1)) * H_SZ]);
                const unsigned long long v8 = __hip_atomic_load(
                    &src[qw], __ATOMIC_RELAXED, __HIP_MEMORY_SCOPE_AGENT);
                *(unsigned long long*)(&Hs[b][qw * 2]) = v8;
            }
            __syncthreads();

            // ---- MAC: acc[b][jj] = sum_{k in [kbase,kbase+16)}
            //      H[b][k] * W[k][2jp+jj] ----
            float acc[4][2];
            #pragma unroll
            for (int b = 0; b < 4; ++b) {
                const float4* hb = (const float4*)(&Hs[b][kbase]);
                float a0 = 0.f, a1 = 0.f;
                #pragma unroll
                for (int q = 0; q < 4; ++q) {
                    const float4 h = hb[q];   // 16-lane broadcast, 2-way bank
                    a0 += h.x * w0[4 * q + 0];
                    a1 += h.x * w1[4 * q + 0];
                    a0 += h.y * w0[4 * q + 1];
                    a1 += h.y * w1[4 * q + 1];
                    a0 += h.z * w0[4 * q + 2];
                    a1 += h.z * w1[4 * q + 2];
                    a0 += h.w * w0[4 * q + 3];
                    a1 += h.w * w1[4 * q + 3];
                }
                acc[b][0] = a0;
                acc[b][1] = a1;
            }
            // combine the 4 in-wave k-segments (sw dimension: lanes ^16, ^32)
            #pragma unroll
            for (int b = 0; b < 4; ++b) {
                #pragma unroll
                for (int jj = 0; jj < 2; ++jj) {
                    acc[b][jj] += __shfl_xor(acc[b][jj], 16);
                    acc[b][jj] += __shfl_xor(acc[b][jj], 32);
                }
            }
            if ((tid & 63) < 16) {
                #pragma unroll
                for (int b = 0; b < 4; ++b) {
                    red[wv][b][2 * jp + 0] = acc[b][0];
                    red[wv][b][2 * jp + 1] = acc[b][1];
                }
            }
            __syncthreads();
        }

        // ---- epilogue: first 128 threads own the 4b x 32j outputs ----
        if (tid < 128) {
            float s = 0.f;
            if (t > 0) {
                #pragma unroll
                for (int wv2 = 0; wv2 < 16; ++wv2) s += red[wv2][eb][ej];
            }
            const float v = fast_tanh(xp + s);
            // publish H_t at the agent coherent point (no fence needed)
            __hip_atomic_store(&HS[eidx], v, __ATOMIC_RELAXED,
                               __HIP_MEMORY_SCOPE_AGENT);
            if (t == S_SZ - 1)
                Hlast[(size_t)(b0 + eb) * H_SZ + col0 + ej] = v;
        }

        // __syncthreads: compiler emits s_waitcnt vmcnt(0) before s_barrier,
        // so all atomic H stores above are agent-visible before we arrive.
        __syncthreads();
        if (tid == 0) {
            __hip_atomic_fetch_add(flag + t, 1u, __ATOMIC_RELAXED,
                                   __HIP_MEMORY_SCOPE_AGENT);
        }
    }
}

extern "C" void kernel_launch(void* const* d_in, const int* in_sizes, int n_in,
                              void* d_out, int out_size, void* d_ws, size_t ws_size,
                              hipStream_t stream) {
    const float* X    = (const float*)d_in[0];  // [B,S,K]
    const float* W_xh = (const float*)d_in[1];  // [K,H]
    const float* W_hh = (const float*)d_in[2];  // [H,H]
    const float* b_h  = (const float*)d_in[3];  // [H]
    float* out = (float*)d_out;
    float* Hlast = out + (size_t)B_SZ * S_SZ * H_SZ;
    unsigned int* cnt = (unsigned int*)d_ws;    // [8][S_SZ] counters

    // zero sync counters (d_ws is re-poisoned before every launch)
    init_cnt<<<(8 * S_SZ + 255) / 256, 256, 0, stream>>>(cnt, 8 * S_SZ);

    // Phase 1: Xp = X @ W_xh + b into d_out's [B,S,H] region.
    dim3 gridA(H_SZ / BN, (B_SZ * S_SZ) / BM);
    proj_gemm<<<gridA, 256, 0, stream>>>(X, W_xh, b_h, out,
                                         B_SZ * S_SZ, H_SZ, K_SZ);

    // Phase 2: all 1024 recurrence steps in one persistent kernel.
    rnn_persist<<<256, 1024, 0, stream>>>(out, W_hh, Hlast, cnt);
}